// Round 1
// baseline (343.429 us; speedup 1.0000x reference)
//
#include <hip/hip_runtime.h>

// Problem constants
#define Bb 2
#define Qq 2048
#define Ss 2048
#define Dd 1024
#define Hh 16
#define AD 64

typedef __attribute__((ext_vector_type(8))) short bf16x8;
typedef __attribute__((ext_vector_type(4))) float f32x4;
typedef unsigned short u16;
typedef unsigned int u32;

__device__ __forceinline__ u16 f2bf(float f) {
  union { float f; u32 u; } v; v.f = f;
  u32 r = v.u + 0x7fffu + ((v.u >> 16) & 1u);  // RNE
  return (u16)(r >> 16);
}
__device__ __forceinline__ float bf2f(u16 h) {
  union { u32 u; float f; } v; v.u = ((u32)h) << 16;
  return v.f;
}

// ---------------- f32 -> bf16 cast ----------------
__global__ __launch_bounds__(256) void cast_bf16_k(const float* __restrict__ in,
                                                   u16* __restrict__ out, int n4) {
  int i = blockIdx.x * 256 + threadIdx.x;
  if (i < n4) {
    float4 v = ((const float4*)in)[i];
    ushort4 o;
    o.x = f2bf(v.x); o.y = f2bf(v.y); o.z = f2bf(v.z); o.w = f2bf(v.w);
    ((ushort4*)out)[i] = o;
  }
}

// ---------------- C = A @ W^T  (A: MxK bf16, W: NxK bf16) ----------------
// 128x128 tile, BK=32, 256 threads = 4 waves in 2x2, each wave 64x64 via 4x4
// mfma_f32_16x16x32_bf16 tiles. LDS stride 40 (pad 8) -> 2-way bank alias (free).
template <int WRITE_F32>
__global__ __launch_bounds__(256) void gemm_bt(const u16* __restrict__ A,
                                               const u16* __restrict__ W,
                                               void* __restrict__ C,
                                               int M, int N, int K) {
  __shared__ u16 As[128 * 40];
  __shared__ u16 Ws[128 * 40];
  const int tid = threadIdx.x;
  const int lane = tid & 63, wave = tid >> 6;
  const int qr = lane & 15, quad = lane >> 4;
  const int m0 = blockIdx.x * 128, n0 = blockIdx.y * 128;
  const int wm = (wave >> 1) * 64, wn = (wave & 1) * 64;
  f32x4 acc[4][4] = {};
  const int r0 = tid >> 2;            // rows 0..63 (and +64 for second chunk)
  const int cc0 = (tid & 3) * 8;      // 8-elem (16B) column chunk

  for (int k0 = 0; k0 < K; k0 += 32) {
    *(int4*)(As + r0 * 40 + cc0)        = *(const int4*)(A + (size_t)(m0 + r0) * K + k0 + cc0);
    *(int4*)(As + (r0 + 64) * 40 + cc0) = *(const int4*)(A + (size_t)(m0 + r0 + 64) * K + k0 + cc0);
    *(int4*)(Ws + r0 * 40 + cc0)        = *(const int4*)(W + (size_t)(n0 + r0) * K + k0 + cc0);
    *(int4*)(Ws + (r0 + 64) * 40 + cc0) = *(const int4*)(W + (size_t)(n0 + r0 + 64) * K + k0 + cc0);
    __syncthreads();
    bf16x8 af[4], bw[4];
#pragma unroll
    for (int i = 0; i < 4; i++)
      af[i] = *(const bf16x8*)(As + (wm + i * 16 + qr) * 40 + quad * 8);
#pragma unroll
    for (int j = 0; j < 4; j++)
      bw[j] = *(const bf16x8*)(Ws + (wn + j * 16 + qr) * 40 + quad * 8);
#pragma unroll
    for (int i = 0; i < 4; i++)
#pragma unroll
      for (int j = 0; j < 4; j++)
        acc[i][j] = __builtin_amdgcn_mfma_f32_16x16x32_bf16(af[i], bw[j], acc[i][j], 0, 0, 0);
    __syncthreads();
  }
  // Epilogue: C/D layout col=lane&15, row=quad*4+reg (verified m89/m91)
#pragma unroll
  for (int i = 0; i < 4; i++)
#pragma unroll
    for (int j = 0; j < 4; j++)
#pragma unroll
      for (int r = 0; r < 4; r++) {
        int row = m0 + wm + i * 16 + quad * 4 + r;
        int col = n0 + wn + j * 16 + qr;
        float v = acc[i][j][r];
        if (WRITE_F32) ((float*)C)[(size_t)row * N + col] = v;
        else           ((u16*)C)[(size_t)row * N + col] = f2bf(v);
      }
}

// ---------------- fused attention ----------------
// block = (q-tile of 64, h, b); 4 waves, wave w owns q-rows [w*16, w*16+16).
// relu^2 normalization is linear in the denominator -> accumulate unnormalized
// P@V and row-sums; divide once at the end. P goes C-layout -> LDS -> A-layout.
__global__ __launch_bounds__(256) void attn_k(const u16* __restrict__ RQ,
                                              const u16* __restrict__ KV,
                                              const int* __restrict__ mask,
                                              const float* __restrict__ nbias,
                                              u16* __restrict__ O) {
  __shared__ u16 Qs[64 * 72];
  __shared__ u16 Ks[64 * 72];
  __shared__ u16 Vt[64 * 72];       // transposed: Vt[d][s]
  __shared__ u16 Ps[4][16 * 72];    // per-wave P strip, A-layout source
  const int tid = threadIdx.x, lane = tid & 63, wave = tid >> 6;
  const int qr = lane & 15, quad = lane >> 4;
  const int q0 = blockIdx.x * 64, h = blockIdx.y, b = blockIdx.z;
  const u16* rqb = RQ + ((size_t)b * Qq + q0) * Dd + h * AD;
  const u16* kb  = KV + ((size_t)b * Ss) * (2 * Dd) + h * AD;
  const u16* vb  = kb + Dd;
  const int* mb  = mask + ((size_t)b * Qq + q0) * Ss;
  const float nb = nbias[0];

  // load Q tile (64 x 64)
#pragma unroll
  for (int c = tid; c < 512; c += 256) {
    int r = c >> 3, cc = (c & 7) * 8;
    *(int4*)(Qs + r * 72 + cc) = *(const int4*)(rqb + (size_t)r * Dd + cc);
  }

  f32x4 acco[4] = {};
  float den[4] = {0.f, 0.f, 0.f, 0.f};

  for (int s0 = 0; s0 < Ss; s0 += 64) {
    // stage K tile
#pragma unroll
    for (int c = tid; c < 512; c += 256) {
      int r = c >> 3, cc = (c & 7) * 8;
      *(int4*)(Ks + r * 72 + cc) = *(const int4*)(kb + (size_t)(s0 + r) * (2 * Dd) + cc);
    }
    // stage V tile transposed
#pragma unroll
    for (int c = tid; c < 512; c += 256) {
      int r = c >> 3, cc = (c & 7) * 8;
      int4 raw = *(const int4*)(vb + (size_t)(s0 + r) * (2 * Dd) + cc);
      u16 tmp[8];
      *(int4*)tmp = raw;
#pragma unroll
      for (int j = 0; j < 8; j++) Vt[(cc + j) * 72 + r] = tmp[j];
    }
    __syncthreads();

    // scores: S = Q @ K^T (K-dim = 64 = 2 mfma k-steps)
    f32x4 asc[4] = {};
    bf16x8 aq0 = *(const bf16x8*)(Qs + (wave * 16 + qr) * 72 + quad * 8);
    bf16x8 aq1 = *(const bf16x8*)(Qs + (wave * 16 + qr) * 72 + 32 + quad * 8);
#pragma unroll
    for (int j = 0; j < 4; j++) {
      bf16x8 bk0 = *(const bf16x8*)(Ks + (j * 16 + qr) * 72 + quad * 8);
      bf16x8 bk1 = *(const bf16x8*)(Ks + (j * 16 + qr) * 72 + 32 + quad * 8);
      asc[j] = __builtin_amdgcn_mfma_f32_16x16x32_bf16(aq0, bk0, asc[j], 0, 0, 0);
      asc[j] = __builtin_amdgcn_mfma_f32_16x16x32_bf16(aq1, bk1, asc[j], 0, 0, 0);
    }
    // mask + relu^2, accumulate denominator, spill P to LDS (A-layout rows)
#pragma unroll
    for (int j = 0; j < 4; j++)
#pragma unroll
      for (int r = 0; r < 4; r++) {
        int qrow = quad * 4 + r;            // local q row (C layout)
        int scol = j * 16 + qr;             // local s col
        float v = asc[j][r] * 0.125f + nb;  // /sqrt(64) + nbias
        int m = mb[(size_t)(wave * 16 + qrow) * Ss + s0 + scol];
        float t = v > 0.f ? v * v : 0.f;
        if (m) t = 0.f;                     // mask True => excluded
        u16 tb = f2bf(t);
        den[r] += bf2f(tb);                 // keep num/den consistent in bf16
        Ps[wave][qrow * 72 + scol] = tb;
      }
    __syncthreads();

    // PV: acco += P @ V  (K-dim = 64 = 2 k-steps)
#pragma unroll
    for (int ks = 0; ks < 2; ks++) {
      bf16x8 ap = *(const bf16x8*)(Ps[wave] + qr * 72 + ks * 32 + quad * 8);
#pragma unroll
      for (int n = 0; n < 4; n++) {
        bf16x8 bv = *(const bf16x8*)(Vt + (n * 16 + qr) * 72 + ks * 32 + quad * 8);
        acco[n] = __builtin_amdgcn_mfma_f32_16x16x32_bf16(ap, bv, acco[n], 0, 0, 0);
      }
    }
    __syncthreads();
  }

  // reduce denominators across the 16 column-lanes of each quad
#pragma unroll
  for (int off = 1; off < 16; off <<= 1)
#pragma unroll
    for (int r = 0; r < 4; r++) den[r] += __shfl_xor(den[r], off, 64);

  u16* ob = O + ((size_t)b * Qq + q0) * Dd + h * AD;
#pragma unroll
  for (int r = 0; r < 4; r++) {
    int qrow = wave * 16 + quad * 4 + r;
    float sc = 1.f / (den[r] + 1e-32f);
#pragma unroll
    for (int n = 0; n < 4; n++) {
      int d = n * 16 + qr;
      ob[(size_t)qrow * Dd + d] = f2bf(acco[n][r] * sc);
    }
  }
}

// ---------------- launch ----------------
extern "C" void kernel_launch(void* const* d_in, const int* in_sizes, int n_in,
                              void* d_out, int out_size, void* d_ws, size_t ws_size,
                              hipStream_t stream) {
  const float* iQ   = (const float*)d_in[0];
  const float* iK   = (const float*)d_in[1];
  const int*   mask = (const int*)d_in[2];
  const float* Wq   = (const float*)d_in[3];
  const float* Wkv  = (const float*)d_in[4];
  const float* Wo   = (const float*)d_in[5];
  const float* nb   = (const float*)d_in[6];

  char* ws = (char*)d_ws;
  u16* Qb   = (u16*)(ws + (size_t)0);          // 8 MB  (4096x1024 bf16)
  u16* Kb   = (u16*)(ws + ((size_t)8  << 20)); // 8 MB
  u16* Wqb  = (u16*)(ws + ((size_t)16 << 20)); // 2 MB
  u16* Wkvb = (u16*)(ws + ((size_t)18 << 20)); // 4 MB
  u16* Wob  = (u16*)(ws + ((size_t)22 << 20)); // 2 MB
  u16* RQ   = (u16*)(ws + ((size_t)24 << 20)); // 8 MB  (4096x1024 bf16)
  u16* KV   = (u16*)(ws + ((size_t)32 << 20)); // 16 MB (4096x2048 bf16)
  u16* Obuf = (u16*)(ws + ((size_t)48 << 20)); // 8 MB  -- total 56 MB of ws

  cast_bf16_k<<<4096, 256, 0, stream>>>(iQ, Qb, 1048576);
  cast_bf16_k<<<4096, 256, 0, stream>>>(iK, Kb, 1048576);
  cast_bf16_k<<<1024, 256, 0, stream>>>(Wq, Wqb, 262144);
  cast_bf16_k<<<2048, 256, 0, stream>>>(Wkv, Wkvb, 524288);
  cast_bf16_k<<<1024, 256, 0, stream>>>(Wo, Wob, 262144);

  gemm_bt<0><<<dim3(32, 8), 256, 0, stream>>>(Qb, Wqb, RQ, 4096, 1024, 1024);
  gemm_bt<0><<<dim3(32, 16), 256, 0, stream>>>(Kb, Wkvb, KV, 4096, 2048, 1024);

  attn_k<<<dim3(32, 16, 2), 256, 0, stream>>>(RQ, KV, mask, nb, Obuf);

  gemm_bt<1><<<dim3(32, 8), 256, 0, stream>>>(Obuf, Wob, d_out, 4096, 1024, 1024);
}

// Round 2
// 313.193 us; speedup vs baseline: 1.0965x; 1.0965x over previous
//
#include <hip/hip_runtime.h>

// Problem constants
#define Bb 2
#define Qq 2048
#define Ss 2048
#define Dd 1024
#define Hh 16
#define AD 64

typedef __attribute__((ext_vector_type(8))) short bf16x8;
typedef __attribute__((ext_vector_type(4))) float f32x4;
typedef unsigned short u16;
typedef unsigned int u32;
typedef unsigned long long u64;

__device__ __forceinline__ u16 f2bf(float f) {
  union { float f; u32 u; } v; v.f = f;
  u32 r = v.u + 0x7fffu + ((v.u >> 16) & 1u);  // RNE
  return (u16)(r >> 16);
}

// ---------------- f32 -> bf16 cast ----------------
__global__ __launch_bounds__(256) void cast_bf16_k(const float* __restrict__ in,
                                                   u16* __restrict__ out, int n4) {
  int i = blockIdx.x * 256 + threadIdx.x;
  if (i < n4) {
    float4 v = ((const float4*)in)[i];
    ushort4 o;
    o.x = f2bf(v.x); o.y = f2bf(v.y); o.z = f2bf(v.z); o.w = f2bf(v.w);
    ((ushort4*)out)[i] = o;
  }
}

// ---------------- mask bit-pack: int32[b][q][s] -> u64[b][q][s/64] ----------------
__global__ __launch_bounds__(256) void maskpack_k(const int* __restrict__ mask,
                                                  u64* __restrict__ mb64) {
  int flat = blockIdx.x * 256 + threadIdx.x;   // total 2*2048*32 = 131072
  int st = flat & 31;
  int q  = (flat >> 5) & 2047;
  int b  = flat >> 16;
  const int4* src = (const int4*)(mask + ((size_t)(b * Qq + q)) * Ss + st * 64);
  u64 bits = 0;
#pragma unroll
  for (int c = 0; c < 16; c++) {
    int4 v = src[c];
    bits |= (u64)(v.x != 0) << (c * 4 + 0);
    bits |= (u64)(v.y != 0) << (c * 4 + 1);
    bits |= (u64)(v.z != 0) << (c * 4 + 2);
    bits |= (u64)(v.w != 0) << (c * 4 + 3);
  }
  mb64[flat] = bits;
}

// ---------------- V transpose: KV V-half -> VT[b][h][d][s] ----------------
__global__ __launch_bounds__(256) void vtrans_k(const u16* __restrict__ KV,
                                                u16* __restrict__ VT) {
  __shared__ u16 T[64 * 72];
  const int tid = threadIdx.x;
  const int s0 = blockIdx.x * 64, h = blockIdx.y, b = blockIdx.z;
#pragma unroll
  for (int c = tid; c < 512; c += 256) {
    int row = c >> 3, col8 = (c & 7) * 8;
    *(int4*)(T + row * 72 + col8) =
        *(const int4*)(KV + ((size_t)(b * Ss + s0 + row)) * (2 * Dd) + Dd + h * AD + col8);
  }
  __syncthreads();
#pragma unroll
  for (int c = tid; c < 512; c += 256) {
    int drow = c >> 3, s8 = (c & 7) * 8;
    u16 tmp[8];
#pragma unroll
    for (int j = 0; j < 8; j++) tmp[j] = T[(s8 + j) * 72 + drow];
    *(int4*)(VT + (((size_t)(b * Hh + h)) * AD + drow) * Ss + s0 + s8) = *(int4*)tmp;
  }
}

// ---------------- C = A @ W^T  (A: MxK bf16, W: NxK bf16) ----------------
template <int WRITE_F32>
__global__ __launch_bounds__(256) void gemm_bt(const u16* __restrict__ A,
                                               const u16* __restrict__ W,
                                               void* __restrict__ C,
                                               int M, int N, int K) {
  __shared__ u16 As[128 * 40];
  __shared__ u16 Ws[128 * 40];
  const int tid = threadIdx.x;
  const int lane = tid & 63, wave = tid >> 6;
  const int qr = lane & 15, quad = lane >> 4;
  const int m0 = blockIdx.x * 128, n0 = blockIdx.y * 128;
  const int wm = (wave >> 1) * 64, wn = (wave & 1) * 64;
  f32x4 acc[4][4] = {};
  const int r0 = tid >> 2;
  const int cc0 = (tid & 3) * 8;

  for (int k0 = 0; k0 < K; k0 += 32) {
    *(int4*)(As + r0 * 40 + cc0)        = *(const int4*)(A + (size_t)(m0 + r0) * K + k0 + cc0);
    *(int4*)(As + (r0 + 64) * 40 + cc0) = *(const int4*)(A + (size_t)(m0 + r0 + 64) * K + k0 + cc0);
    *(int4*)(Ws + r0 * 40 + cc0)        = *(const int4*)(W + (size_t)(n0 + r0) * K + k0 + cc0);
    *(int4*)(Ws + (r0 + 64) * 40 + cc0) = *(const int4*)(W + (size_t)(n0 + r0 + 64) * K + k0 + cc0);
    __syncthreads();
    bf16x8 af[4], bw[4];
#pragma unroll
    for (int i = 0; i < 4; i++)
      af[i] = *(const bf16x8*)(As + (wm + i * 16 + qr) * 40 + quad * 8);
#pragma unroll
    for (int j = 0; j < 4; j++)
      bw[j] = *(const bf16x8*)(Ws + (wn + j * 16 + qr) * 40 + quad * 8);
#pragma unroll
    for (int i = 0; i < 4; i++)
#pragma unroll
      for (int j = 0; j < 4; j++)
        acc[i][j] = __builtin_amdgcn_mfma_f32_16x16x32_bf16(af[i], bw[j], acc[i][j], 0, 0, 0);
    __syncthreads();
  }
#pragma unroll
  for (int i = 0; i < 4; i++)
#pragma unroll
    for (int j = 0; j < 4; j++)
#pragma unroll
      for (int r = 0; r < 4; r++) {
        int row = m0 + wm + i * 16 + quad * 4 + r;
        int col = n0 + wn + j * 16 + qr;
        float v = acc[i][j][r];
        if (WRITE_F32) ((float*)C)[(size_t)row * N + col] = v;
        else           ((u16*)C)[(size_t)row * N + col] = f2bf(v);
      }
}

// ---------------- fused attention v2 ----------------
// Block = (q-tile 64, h, b), 4 waves. Scores computed TRANSPOSED:
// St[s][q] = K @ Q^T  (A=K rows, B=Q rows). Wave w owns s-stripe [w*16,w*16+16).
// C-layout regs run along m=s -> P spills to Ps[q][s] as packed b64 writes.
// PV: A = Ps rows (q,k=s), B = Vts rows (d,k=s) from pre-transposed VT.
// relu^2 norm is linear -> unnormalized accumulate + single divide at end.
__global__ __launch_bounds__(256, 4) void attn_k(const u16* __restrict__ RQ,
                                                 const u16* __restrict__ KV,
                                                 const u16* __restrict__ VT,
                                                 const u64* __restrict__ mb64,
                                                 const float* __restrict__ nbias,
                                                 u16* __restrict__ O) {
  __shared__ u16 Qs[64 * 72];
  __shared__ u16 Ks[64 * 72];
  __shared__ u16 Vts[64 * 72];     // Vts[d][s]
  __shared__ u16 Ps[64 * 72];      // Ps[q][s]
  __shared__ float denS[4 * 64];
  const int tid = threadIdx.x, lane = tid & 63, wave = tid >> 6;
  const int qr = lane & 15, quad = lane >> 4;
  const int q0 = blockIdx.x * 64, h = blockIdx.y, b = blockIdx.z;
  const u16* rqb = RQ + ((size_t)(b * Qq + q0)) * Dd + h * AD;
  const u16* kb  = KV + ((size_t)b * Ss) * (2 * Dd) + h * AD;
  const u16* vtb = VT + ((size_t)(b * Hh + h)) * AD * Ss;
  const u64* mbase = mb64 + ((size_t)(b * Qq + q0)) * 32;
  const float nb = nbias[0];

  // stage Q tile once
#pragma unroll
  for (int c = tid; c < 512; c += 256) {
    int r = c >> 3, cc = (c & 7) * 8;
    *(int4*)(Qs + r * 72 + cc) = *(const int4*)(rqb + (size_t)r * Dd + cc);
  }
  __syncthreads();
  // hoist loop-invariant Q fragments (B operand: n=q rows)
  bf16x8 bq[4][2];
#pragma unroll
  for (int j = 0; j < 4; j++)
#pragma unroll
    for (int kk = 0; kk < 2; kk++)
      bq[j][kk] = *(const bf16x8*)(Qs + (j * 16 + qr) * 72 + kk * 32 + quad * 8);

  f32x4 acco[4] = {};
  float den[4] = {0.f, 0.f, 0.f, 0.f};
  const int sh = wave * 16 + quad * 4;   // this lane's s-offset within tile

  for (int t = 0; t < 32; t++) {
    __syncthreads();   // (A) prev PV done -> safe to overwrite Ks/Vts
    const int s0 = t * 64;
#pragma unroll
    for (int c = tid; c < 512; c += 256) {
      int r = c >> 3, cc = (c & 7) * 8;
      *(int4*)(Ks + r * 72 + cc) = *(const int4*)(kb + (size_t)(s0 + r) * (2 * Dd) + cc);
    }
#pragma unroll
    for (int c = tid; c < 512; c += 256) {
      int dr = c >> 3, s8 = (c & 7) * 8;
      *(int4*)(Vts + dr * 72 + s8) = *(const int4*)(vtb + (size_t)dr * Ss + s0 + s8);
    }
    // per-lane mask words (row q0+j*16+qr, this s-tile), pre-shifted to lane's s range
    u32 mbits[4];
#pragma unroll
    for (int j = 0; j < 4; j++) {
      u64 m = mbase[(size_t)(j * 16 + qr) * 32 + t];
      mbits[j] = (u32)(m >> sh);
    }
    __syncthreads();   // (B) tiles staged

    // St = K @ Q^T : wave w computes s-rows [w*16, w*16+16)
    f32x4 asc[4] = {};
    bf16x8 ak0 = *(const bf16x8*)(Ks + (wave * 16 + qr) * 72 + quad * 8);
    bf16x8 ak1 = *(const bf16x8*)(Ks + (wave * 16 + qr) * 72 + 32 + quad * 8);
#pragma unroll
    for (int j = 0; j < 4; j++) {
      asc[j] = __builtin_amdgcn_mfma_f32_16x16x32_bf16(ak0, bq[j][0], asc[j], 0, 0, 0);
      asc[j] = __builtin_amdgcn_mfma_f32_16x16x32_bf16(ak1, bq[j][1], asc[j], 0, 0, 0);
    }
    // mask + relu^2 ; truncate to bf16; accumulate SAME truncated vals into den
#pragma unroll
    for (int j = 0; j < 4; j++) {
      u32 th[4];
#pragma unroll
      for (int r = 0; r < 4; r++) {
        float v = __builtin_fmaf(asc[j][r], 0.125f, nb);
        float tt = fmaxf(v, 0.f);
        tt = tt * tt;
        if ((mbits[j] >> r) & 1) tt = 0.f;
        union { float f; u32 u; } cv; cv.f = tt;
        th[r] = cv.u & 0xffff0000u;
        union { u32 u; float f; } tv; tv.u = th[r];
        den[j] += tv.f;
      }
      uint2 pk;
      pk.x = (th[0] >> 16) | th[1];
      pk.y = (th[2] >> 16) | th[3];
      *(uint2*)(Ps + (j * 16 + qr) * 72 + sh) = pk;
    }
    __syncthreads();   // (C) Ps ready

    // PV: O[q][d] += P @ V. wave w owns q-rows [w*16,w*16+16).
#pragma unroll
    for (int kk = 0; kk < 2; kk++) {
      bf16x8 ap = *(const bf16x8*)(Ps + (wave * 16 + qr) * 72 + kk * 32 + quad * 8);
#pragma unroll
      for (int nn = 0; nn < 4; nn++) {
        bf16x8 bv = *(const bf16x8*)(Vts + (nn * 16 + qr) * 72 + kk * 32 + quad * 8);
        acco[nn] = __builtin_amdgcn_mfma_f32_16x16x32_bf16(ap, bv, acco[nn], 0, 0, 0);
      }
    }
  }

  // reduce den over the 4 quads (lane bits 4,5), then across waves via LDS
#pragma unroll
  for (int j = 0; j < 4; j++) {
    den[j] += __shfl_xor(den[j], 16, 64);
    den[j] += __shfl_xor(den[j], 32, 64);
  }
  if (lane < 16) {
#pragma unroll
    for (int j = 0; j < 4; j++) denS[wave * 64 + j * 16 + qr] = den[j];
  }
  __syncthreads();

  u16* ob = O + ((size_t)(b * Qq + q0)) * Dd + h * AD;
#pragma unroll
  for (int r = 0; r < 4; r++) {
    int qrow = wave * 16 + quad * 4 + r;
    float dn = denS[qrow] + denS[64 + qrow] + denS[128 + qrow] + denS[192 + qrow];
    float sc = 1.f / (dn + 1e-32f);
#pragma unroll
    for (int nn = 0; nn < 4; nn++) {
      int d = nn * 16 + qr;
      ob[(size_t)qrow * Dd + d] = f2bf(acco[nn][r] * sc);
    }
  }
}

// ---------------- launch ----------------
extern "C" void kernel_launch(void* const* d_in, const int* in_sizes, int n_in,
                              void* d_out, int out_size, void* d_ws, size_t ws_size,
                              hipStream_t stream) {
  const float* iQ   = (const float*)d_in[0];
  const float* iK   = (const float*)d_in[1];
  const int*   mask = (const int*)d_in[2];
  const float* Wq   = (const float*)d_in[3];
  const float* Wkv  = (const float*)d_in[4];
  const float* Wo   = (const float*)d_in[5];
  const float* nb   = (const float*)d_in[6];

  char* ws = (char*)d_ws;
  u16* Qb   = (u16*)(ws + (size_t)0);          // 8 MB
  u16* Kb   = (u16*)(ws + ((size_t)8  << 20)); // 8 MB
  u16* Wqb  = (u16*)(ws + ((size_t)16 << 20)); // 2 MB
  u16* Wkvb = (u16*)(ws + ((size_t)18 << 20)); // 4 MB
  u16* Wob  = (u16*)(ws + ((size_t)22 << 20)); // 2 MB
  u16* RQ   = (u16*)(ws + ((size_t)24 << 20)); // 8 MB
  u16* KV   = (u16*)(ws + ((size_t)32 << 20)); // 16 MB
  u16* Obuf = (u16*)(ws + ((size_t)48 << 20)); // 8 MB
  u16* VT   = (u16*)(ws + ((size_t)56 << 20)); // 8 MB
  u64* MB   = (u64*)(ws + ((size_t)64 << 20)); // 1 MB  -- total 65 MB

  cast_bf16_k<<<4096, 256, 0, stream>>>(iQ, Qb, 1048576);
  cast_bf16_k<<<4096, 256, 0, stream>>>(iK, Kb, 1048576);
  cast_bf16_k<<<1024, 256, 0, stream>>>(Wq, Wqb, 262144);
  cast_bf16_k<<<2048, 256, 0, stream>>>(Wkv, Wkvb, 524288);
  cast_bf16_k<<<1024, 256, 0, stream>>>(Wo, Wob, 262144);
  maskpack_k<<<512, 256, 0, stream>>>(mask, MB);

  gemm_bt<0><<<dim3(32, 8), 256, 0, stream>>>(Qb, Wqb, RQ, 4096, 1024, 1024);
  gemm_bt<0><<<dim3(32, 16), 256, 0, stream>>>(Kb, Wkvb, KV, 4096, 2048, 1024);
  vtrans_k<<<dim3(32, 16, 2), 256, 0, stream>>>(KV, VT);

  attn_k<<<dim3(32, 16, 2), 256, 0, stream>>>(RQ, KV, VT, MB, nb, Obuf);

  gemm_bt<1><<<dim3(32, 8), 256, 0, stream>>>(Obuf, Wob, d_out, 4096, 1024, 1024);
}

// Round 3
// 293.200 us; speedup vs baseline: 1.1713x; 1.0682x over previous
//
#include <hip/hip_runtime.h>

// Problem constants
#define Bb 2
#define Qq 2048
#define Ss 2048
#define Dd 1024
#define Hh 16
#define AD 64

typedef __attribute__((ext_vector_type(8))) short bf16x8;
typedef __attribute__((ext_vector_type(4))) float f32x4;
typedef unsigned short u16;
typedef unsigned int u32;
typedef unsigned long long u64;

__device__ __forceinline__ u16 f2bf(float f) {
  union { float f; u32 u; } v; v.f = f;
  u32 r = v.u + 0x7fffu + ((v.u >> 16) & 1u);  // RNE
  return (u16)(r >> 16);
}

// async 16B global->LDS DMA (dest = wave-uniform base + lane*16)
__device__ __forceinline__ void gld16(const u16* g, u16* l) {
  __builtin_amdgcn_global_load_lds(
      (const __attribute__((address_space(1))) unsigned int*)g,
      (__attribute__((address_space(3))) unsigned int*)l, 16, 0, 0);
}

// ---------------- fused f32 -> bf16 cast for all 5 inputs ----------------
__global__ __launch_bounds__(256) void cast_all_k(const float* __restrict__ iQ,
                                                  const float* __restrict__ iK,
                                                  const float* __restrict__ Wq,
                                                  const float* __restrict__ Wkv,
                                                  const float* __restrict__ Wo,
                                                  u16* __restrict__ Qb, u16* __restrict__ Kb,
                                                  u16* __restrict__ Wqb, u16* __restrict__ Wkvb,
                                                  u16* __restrict__ Wob) {
  int i = blockIdx.x * 256 + threadIdx.x;   // float4 index, total 3145728
  const float* src; u16* dst; int off;
  if (i < 1048576)      { src = iQ;  dst = Qb;   off = 0; }
  else if (i < 2097152) { src = iK;  dst = Kb;   off = 1048576; }
  else if (i < 2359296) { src = Wq;  dst = Wqb;  off = 2097152; }
  else if (i < 2883584) { src = Wkv; dst = Wkvb; off = 2359296; }
  else                  { src = Wo;  dst = Wob;  off = 2883584; }
  int j = i - off;
  float4 v = ((const float4*)src)[j];
  ushort4 o;
  o.x = f2bf(v.x); o.y = f2bf(v.y); o.z = f2bf(v.z); o.w = f2bf(v.w);
  ((ushort4*)dst)[j] = o;
}

// ---------------- mask bit-pack: int32[b][q][s] -> u64[b][q][s/64] ----------------
__global__ __launch_bounds__(256) void maskpack_k(const int* __restrict__ mask,
                                                  u64* __restrict__ mb64) {
  int flat = blockIdx.x * 256 + threadIdx.x;   // total 2*2048*32 = 131072
  int st = flat & 31;
  int q  = (flat >> 5) & 2047;
  int b  = flat >> 16;
  const int4* src = (const int4*)(mask + ((size_t)(b * Qq + q)) * Ss + st * 64);
  u64 bits = 0;
#pragma unroll
  for (int c = 0; c < 16; c++) {
    int4 v = src[c];
    bits |= (u64)(v.x != 0) << (c * 4 + 0);
    bits |= (u64)(v.y != 0) << (c * 4 + 1);
    bits |= (u64)(v.z != 0) << (c * 4 + 2);
    bits |= (u64)(v.w != 0) << (c * 4 + 3);
  }
  mb64[flat] = bits;
}

// ---------------- V transpose: KV V-half -> VT[b][h][d][s] ----------------
__global__ __launch_bounds__(256) void vtrans_k(const u16* __restrict__ KV,
                                                u16* __restrict__ VT) {
  __shared__ u16 T[64 * 72];
  const int tid = threadIdx.x;
  const int s0 = blockIdx.x * 64, h = blockIdx.y, b = blockIdx.z;
#pragma unroll
  for (int c = tid; c < 512; c += 256) {
    int row = c >> 3, col8 = (c & 7) * 8;
    *(int4*)(T + row * 72 + col8) =
        *(const int4*)(KV + ((size_t)(b * Ss + s0 + row)) * (2 * Dd) + Dd + h * AD + col8);
  }
  __syncthreads();
#pragma unroll
  for (int c = tid; c < 512; c += 256) {
    int drow = c >> 3, s8 = (c & 7) * 8;
    u16 tmp[8];
#pragma unroll
    for (int j = 0; j < 8; j++) tmp[j] = T[(s8 + j) * 72 + drow];
    *(int4*)(VT + (((size_t)(b * Hh + h)) * AD + drow) * Ss + s0 + s8) = *(int4*)tmp;
  }
}

// ---------------- C = A @ W^T, m97-style: global_load_lds + XOR swizzle ----------
// As/Ws: [128][32] u16 (64B/row = 4 16B chunks). chunk c stored at c^((row>>1)&3).
// Fragment ds_read_b128: bank-group = ((row&1)*16 + c'*4)%32 -> 2-way (free).
template <int WRITE_F32>
__global__ __launch_bounds__(256) void gemm_bt(const u16* __restrict__ A,
                                               const u16* __restrict__ W,
                                               void* __restrict__ C,
                                               int M, int N, int K) {
  __shared__ u16 As[128 * 32];
  __shared__ u16 Ws[128 * 32];
  const int tid = threadIdx.x;
  const int lane = tid & 63, wave = tid >> 6;
  const int qr = lane & 15, quad = lane >> 4;
  const int m0 = blockIdx.x * 128, n0 = blockIdx.y * 128;
  const int wm = (wave >> 1) * 64, wn = (wave & 1) * 64;
  f32x4 acc[4][4] = {};
  const int sr = tid >> 2;           // 0..63 staging row
  const int sc = tid & 3;            // dest chunk c'
  const u16* arow1 = A + (size_t)(m0 + sr) * K;
  const u16* arow2 = A + (size_t)(m0 + sr + 64) * K;
  const u16* wrow1 = W + (size_t)(n0 + sr) * K;
  const u16* wrow2 = W + (size_t)(n0 + sr + 64) * K;
  const int gc1 = (sc ^ ((sr >> 1) & 3)) * 8;          // global col offset, rows 0..63
  const int gc2 = (sc ^ (((sr + 64) >> 1) & 3)) * 8;   // rows 64..127
  u16* ld_a1 = As + sr * 32 + sc * 8;
  u16* ld_a2 = As + (sr + 64) * 32 + sc * 8;
  u16* ld_w1 = Ws + sr * 32 + sc * 8;
  u16* ld_w2 = Ws + (sr + 64) * 32 + sc * 8;

  for (int k0 = 0; k0 < K; k0 += 32) {
    gld16(arow1 + k0 + gc1, ld_a1);
    gld16(arow2 + k0 + gc2, ld_a2);
    gld16(wrow1 + k0 + gc1, ld_w1);
    gld16(wrow2 + k0 + gc2, ld_w2);
    __syncthreads();
    bf16x8 af[4], bw[4];
#pragma unroll
    for (int i = 0; i < 4; i++) {
      int row = wm + i * 16 + qr;
      af[i] = *(const bf16x8*)(As + row * 32 + (quad ^ ((row >> 1) & 3)) * 8);
    }
#pragma unroll
    for (int j = 0; j < 4; j++) {
      int row = wn + j * 16 + qr;
      bw[j] = *(const bf16x8*)(Ws + row * 32 + (quad ^ ((row >> 1) & 3)) * 8);
    }
#pragma unroll
    for (int i = 0; i < 4; i++)
#pragma unroll
      for (int j = 0; j < 4; j++)
        acc[i][j] = __builtin_amdgcn_mfma_f32_16x16x32_bf16(af[i], bw[j], acc[i][j], 0, 0, 0);
    __syncthreads();
  }
#pragma unroll
  for (int i = 0; i < 4; i++)
#pragma unroll
    for (int j = 0; j < 4; j++)
#pragma unroll
      for (int r = 0; r < 4; r++) {
        int row = m0 + wm + i * 16 + quad * 4 + r;
        int col = n0 + wn + j * 16 + qr;
        float v = acc[i][j][r];
        if (WRITE_F32) ((float*)C)[(size_t)row * N + col] = v;
        else           ((u16*)C)[(size_t)row * N + col] = f2bf(v);
      }
}

// ---------------- fused attention v3 ----------------
// Block = (q-tile 64, h, b), 4 waves, S-tile 128 (16 iters, 3 barriers each).
// Async global_load_lds staging for K and Vt; Q fragments direct from global.
// Scores transposed: St[s][q] = K @ Q^T; Ps[q][s] via packed b64 writes.
// All LDS arrays XOR-swizzled at 16B chunks: c' = c ^ (row & 7).
__global__ __launch_bounds__(256) void attn_k(const u16* __restrict__ RQ,
                                              const u16* __restrict__ KV,
                                              const u16* __restrict__ VT,
                                              const u64* __restrict__ mb64,
                                              const float* __restrict__ nbias,
                                              u16* __restrict__ O) {
  __shared__ u16 Ks[128 * 64];    // [s][d], 8 chunks/row, swizzled
  __shared__ u16 Vts[64 * 128];   // [d][s], 16 chunks/row, swizzled (low3 xor)
  __shared__ u16 Ps[64 * 128];    // [q][s], swizzled
  __shared__ float denS[256];
  const int tid = threadIdx.x, lane = tid & 63, wave = tid >> 6;
  const int qr = lane & 15, quad = lane >> 4;
  const int q0 = blockIdx.x * 64, h = blockIdx.y, b = blockIdx.z;
  const u16* rqb = RQ + ((size_t)(b * Qq + q0)) * Dd + h * AD;
  const u16* kb  = KV + ((size_t)b * Ss) * (2 * Dd) + h * AD;
  const u16* vtb = VT + ((size_t)(b * Hh + h)) * AD * Ss;
  const u64* mbase = mb64 + ((size_t)(b * Qq + q0)) * 32;
  const float nb = nbias[0];

  // Q fragments (B operand: n=q, k=d) straight from global
  bf16x8 bq[4][2];
#pragma unroll
  for (int j = 0; j < 4; j++)
#pragma unroll
    for (int kk = 0; kk < 2; kk++)
      bq[j][kk] = *(const bf16x8*)(rqb + (size_t)(j * 16 + qr) * Dd + kk * 32 + quad * 8);

  f32x4 acco[4] = {};
  float den[4] = {0.f, 0.f, 0.f, 0.f};

  // staging decompositions
  const int kr = tid >> 3, kc = tid & 7;     // Ks: 32 rows x 8 chunks per issue
  const int vr = tid >> 4, vc = tid & 15;    // Vts: 16 rows x 16 chunks per issue
  const int mshift = (wave & 1) * 32 + quad * 4;

  for (int t = 0; t < 16; t++) {
    __syncthreads();   // (1) prev PV reads of Vts/Ps done -> safe to restage
    const int s0 = t * 128;
#pragma unroll
    for (int is = 0; is < 4; is++) {
      int row = is * 32 + kr;
      gld16(kb + (size_t)(s0 + row) * (2 * Dd) + (kc ^ (row & 7)) * 8,
            Ks + row * 64 + kc * 8);
    }
#pragma unroll
    for (int is = 0; is < 4; is++) {
      int row = is * 16 + vr;
      gld16(vtb + (size_t)row * Ss + s0 + ((vc ^ (row & 7)) & 15) * 8,
            Vts + row * 128 + vc * 8);
    }
    // mask words (overlap with DMA): q-row j*16+qr, 64-s granule = 2t + (wave>>1)
    u64 mw[4];
#pragma unroll
    for (int j = 0; j < 4; j++)
      mw[j] = mbase[(size_t)(j * 16 + qr) * 32 + t * 2 + (wave >> 1)];
    __syncthreads();   // (2) tiles staged (barrier drains vmcnt)

    // St = K @ Q^T : wave covers s-rows [wave*32, wave*32+32) via mi
    f32x4 asc[2][4] = {};
#pragma unroll
    for (int mi = 0; mi < 2; mi++) {
      int row = wave * 32 + mi * 16 + qr;
      bf16x8 ak0 = *(const bf16x8*)(Ks + row * 64 + ((0 + quad) ^ (qr & 7)) * 8);
      bf16x8 ak1 = *(const bf16x8*)(Ks + row * 64 + ((4 + quad) ^ (qr & 7)) * 8);
#pragma unroll
      for (int j = 0; j < 4; j++) {
        asc[mi][j] = __builtin_amdgcn_mfma_f32_16x16x32_bf16(ak0, bq[j][0], asc[mi][j], 0, 0, 0);
        asc[mi][j] = __builtin_amdgcn_mfma_f32_16x16x32_bf16(ak1, bq[j][1], asc[mi][j], 0, 0, 0);
      }
    }
    // mask + relu^2, truncate to bf16, same values into denominator
#pragma unroll
    for (int mi = 0; mi < 2; mi++) {
      int G = wave * 4 + mi * 2 + (quad >> 1);          // 16B chunk of s
#pragma unroll
      for (int j = 0; j < 4; j++) {
        u32 mbits = (u32)(mw[j] >> (mshift + mi * 16));
        u32 th[4];
#pragma unroll
        for (int r = 0; r < 4; r++) {
          float v = __builtin_fmaf(asc[mi][j][r], 0.125f, nb);
          float tt = fmaxf(v, 0.f);
          tt = tt * tt;
          if ((mbits >> r) & 1) tt = 0.f;
          union { float f; u32 u; } cv; cv.f = tt;
          th[r] = cv.u & 0xffff0000u;
          union { u32 u; float f; } tv; tv.u = th[r];
          den[j] += tv.f;
        }
        uint2 pk;
        pk.x = (th[0] >> 16) | th[1];
        pk.y = (th[2] >> 16) | th[3];
        int q = j * 16 + qr;
        *(uint2*)(Ps + q * 128 + (G ^ (qr & 7)) * 8 + (quad & 1) * 4) = pk;
      }
    }
    __syncthreads();   // (3) Ps ready

    // PV: O[q][d] += P @ V over k=s=128 (4 k-steps)
#pragma unroll
    for (int kk = 0; kk < 4; kk++) {
      bf16x8 ap = *(const bf16x8*)(Ps + (wave * 16 + qr) * 128 +
                                   ((kk * 4 + quad) ^ (qr & 7)) * 8);
#pragma unroll
      for (int nn = 0; nn < 4; nn++) {
        int row = nn * 16 + qr;
        bf16x8 bv = *(const bf16x8*)(Vts + row * 128 +
                                     ((kk * 4 + quad) ^ (qr & 7)) * 8);
        acco[nn] = __builtin_amdgcn_mfma_f32_16x16x32_bf16(ap, bv, acco[nn], 0, 0, 0);
      }
    }
  }

  // reduce den over quads (lane bits 4,5), then across waves via LDS
#pragma unroll
  for (int j = 0; j < 4; j++) {
    den[j] += __shfl_xor(den[j], 16, 64);
    den[j] += __shfl_xor(den[j], 32, 64);
  }
  __syncthreads();
  if (lane < 16) {
#pragma unroll
    for (int j = 0; j < 4; j++) denS[wave * 64 + j * 16 + qr] = den[j];
  }
  __syncthreads();

  u16* ob = O + ((size_t)(b * Qq + q0)) * Dd + h * AD;
#pragma unroll
  for (int r = 0; r < 4; r++) {
    int qrow = wave * 16 + quad * 4 + r;
    float dn = denS[qrow] + denS[64 + qrow] + denS[128 + qrow] + denS[192 + qrow];
    float sc = 1.f / (dn + 1e-32f);
#pragma unroll
    for (int nn = 0; nn < 4; nn++) {
      int d = nn * 16 + qr;
      ob[(size_t)qrow * Dd + d] = f2bf(acco[nn][r] * sc);
    }
  }
}

// ---------------- launch ----------------
extern "C" void kernel_launch(void* const* d_in, const int* in_sizes, int n_in,
                              void* d_out, int out_size, void* d_ws, size_t ws_size,
                              hipStream_t stream) {
  const float* iQ   = (const float*)d_in[0];
  const float* iK   = (const float*)d_in[1];
  const int*   mask = (const int*)d_in[2];
  const float* Wq   = (const float*)d_in[3];
  const float* Wkv  = (const float*)d_in[4];
  const float* Wo   = (const float*)d_in[5];
  const float* nb   = (const float*)d_in[6];

  char* ws = (char*)d_ws;
  u16* Qb   = (u16*)(ws + (size_t)0);          // 8 MB
  u16* Kb   = (u16*)(ws + ((size_t)8  << 20)); // 8 MB
  u16* Wqb  = (u16*)(ws + ((size_t)16 << 20)); // 2 MB
  u16* Wkvb = (u16*)(ws + ((size_t)18 << 20)); // 4 MB
  u16* Wob  = (u16*)(ws + ((size_t)22 << 20)); // 2 MB
  u16* RQ   = (u16*)(ws + ((size_t)24 << 20)); // 8 MB
  u16* KV   = (u16*)(ws + ((size_t)32 << 20)); // 16 MB
  u16* Obuf = (u16*)(ws + ((size_t)48 << 20)); // 8 MB
  u16* VT   = (u16*)(ws + ((size_t)56 << 20)); // 8 MB
  u64* MB   = (u64*)(ws + ((size_t)64 << 20)); // 1 MB  -- total 65 MB

  cast_all_k<<<12288, 256, 0, stream>>>(iQ, iK, Wq, Wkv, Wo, Qb, Kb, Wqb, Wkvb, Wob);
  maskpack_k<<<512, 256, 0, stream>>>(mask, MB);

  gemm_bt<0><<<dim3(32, 8), 256, 0, stream>>>(Qb, Wqb, RQ, 4096, 1024, 1024);
  gemm_bt<0><<<dim3(32, 16), 256, 0, stream>>>(Kb, Wkvb, KV, 4096, 2048, 1024);
  vtrans_k<<<dim3(32, 16, 2), 256, 0, stream>>>(KV, VT);

  attn_k<<<dim3(32, 16, 2), 256, 0, stream>>>(RQ, KV, VT, MB, nb, Obuf);

  gemm_bt<1><<<dim3(32, 8), 256, 0, stream>>>(Obuf, Wob, d_out, 4096, 1024, 1024);
}

// Round 4
// 267.365 us; speedup vs baseline: 1.2845x; 1.0966x over previous
//
#include <hip/hip_runtime.h>

// Problem constants
#define Bb 2
#define Qq 2048
#define Ss 2048
#define Dd 1024
#define Hh 16
#define AD 64

typedef __attribute__((ext_vector_type(8))) short bf16x8;
typedef __attribute__((ext_vector_type(4))) short bf16x4;
typedef __attribute__((ext_vector_type(4))) float f32x4;
typedef unsigned short u16;
typedef unsigned int u32;
typedef unsigned long long u64;

__device__ __forceinline__ u16 f2bf(float f) {
  union { float f; u32 u; } v; v.f = f;
  u32 r = v.u + 0x7fffu + ((v.u >> 16) & 1u);  // RNE
  return (u16)(r >> 16);
}

// async 16B global->LDS DMA (dest = wave-uniform base + lane*16)
__device__ __forceinline__ void gld16(const u16* g, u16* l) {
  __builtin_amdgcn_global_load_lds(
      (const __attribute__((address_space(1))) unsigned int*)g,
      (__attribute__((address_space(3))) unsigned int*)l, 16, 0, 0);
}

// ---------------- fused f32 -> bf16 cast for all 5 inputs ----------------
__global__ __launch_bounds__(256) void cast_all_k(const float* __restrict__ iQ,
                                                  const float* __restrict__ iK,
                                                  const float* __restrict__ Wq,
                                                  const float* __restrict__ Wkv,
                                                  const float* __restrict__ Wo,
                                                  u16* __restrict__ Qb, u16* __restrict__ Kb,
                                                  u16* __restrict__ Wqb, u16* __restrict__ Wkvb,
                                                  u16* __restrict__ Wob) {
  int i = blockIdx.x * 256 + threadIdx.x;   // float4 index, total 3145728
  const float* src; u16* dst; int off;
  if (i < 1048576)      { src = iQ;  dst = Qb;   off = 0; }
  else if (i < 2097152) { src = iK;  dst = Kb;   off = 1048576; }
  else if (i < 2359296) { src = Wq;  dst = Wqb;  off = 2097152; }
  else if (i < 2883584) { src = Wkv; dst = Wkvb; off = 2359296; }
  else                  { src = Wo;  dst = Wob;  off = 2883584; }
  int j = i - off;
  float4 v = ((const float4*)src)[j];
  ushort4 o;
  o.x = f2bf(v.x); o.y = f2bf(v.y); o.z = f2bf(v.z); o.w = f2bf(v.w);
  ((ushort4*)dst)[j] = o;
}

// ---------------- mask bit-pack: int32[b][q][s] -> u64[b][q][s/64] ----------------
__global__ __launch_bounds__(256) void maskpack_k(const int* __restrict__ mask,
                                                  u64* __restrict__ mb64) {
  int flat = blockIdx.x * 256 + threadIdx.x;   // total 2*2048*32 = 131072
  int st = flat & 31;
  int q  = (flat >> 5) & 2047;
  int b  = flat >> 16;
  const int4* src = (const int4*)(mask + ((size_t)(b * Qq + q)) * Ss + st * 64);
  u64 bits = 0;
#pragma unroll
  for (int c = 0; c < 16; c++) {
    int4 v = src[c];
    bits |= (u64)(v.x != 0) << (c * 4 + 0);
    bits |= (u64)(v.y != 0) << (c * 4 + 1);
    bits |= (u64)(v.z != 0) << (c * 4 + 2);
    bits |= (u64)(v.w != 0) << (c * 4 + 3);
  }
  mb64[flat] = bits;
}

// ---------------- V transpose: KV V-half -> VT[b][h][d][s] ----------------
__global__ __launch_bounds__(256) void vtrans_k(const u16* __restrict__ KV,
                                                u16* __restrict__ VT) {
  __shared__ u16 T[64 * 72];
  const int tid = threadIdx.x;
  const int s0 = blockIdx.x * 64, h = blockIdx.y, b = blockIdx.z;
#pragma unroll
  for (int c = tid; c < 512; c += 256) {
    int row = c >> 3, col8 = (c & 7) * 8;
    *(int4*)(T + row * 72 + col8) =
        *(const int4*)(KV + ((size_t)(b * Ss + s0 + row)) * (2 * Dd) + Dd + h * AD + col8);
  }
  __syncthreads();
#pragma unroll
  for (int c = tid; c < 512; c += 256) {
    int drow = c >> 3, s8 = (c & 7) * 8;
    u16 tmp[8];
#pragma unroll
    for (int j = 0; j < 8; j++) tmp[j] = T[(s8 + j) * 72 + drow];
    *(int4*)(VT + (((size_t)(b * Hh + h)) * AD + drow) * Ss + s0 + s8) = *(int4*)tmp;
  }
}

// ---------------- C = A @ W^T, 128x64 tile, global_load_lds + XOR swizzle --------
// As[128][32], Ws[64][32] u16; chunk c stored at c^((row>>1)&3) -> frag reads
// spread over all 32 banks (conflict-free). 4 waves in 2x2 over (m64, n32).
template <int WRITE_F32>
__global__ __launch_bounds__(256) void gemm_bt(const u16* __restrict__ A,
                                               const u16* __restrict__ W,
                                               void* __restrict__ C,
                                               int M, int N, int K) {
  __shared__ u16 As[128 * 32];
  __shared__ u16 Ws[64 * 32];
  const int tid = threadIdx.x;
  const int lane = tid & 63, wave = tid >> 6;
  const int qr = lane & 15, quad = lane >> 4;
  const int m0 = blockIdx.x * 128, n0 = blockIdx.y * 64;
  const int wm = (wave >> 1) * 64, wn = (wave & 1) * 32;
  f32x4 acc[4][2] = {};
  const int sr = tid >> 2;           // 0..63 staging row
  const int sc = tid & 3;            // dest chunk
  const u16* arow1 = A + (size_t)(m0 + sr) * K;
  const u16* arow2 = A + (size_t)(m0 + sr + 64) * K;
  const u16* wrow1 = W + (size_t)(n0 + sr) * K;
  const int gc1 = (sc ^ ((sr >> 1) & 3)) * 8;
  const int gc2 = (sc ^ (((sr + 64) >> 1) & 3)) * 8;
  u16* ld_a1 = As + sr * 32 + sc * 8;
  u16* ld_a2 = As + (sr + 64) * 32 + sc * 8;
  u16* ld_w1 = Ws + sr * 32 + sc * 8;

  for (int k0 = 0; k0 < K; k0 += 32) {
    gld16(arow1 + k0 + gc1, ld_a1);
    gld16(arow2 + k0 + gc2, ld_a2);
    gld16(wrow1 + k0 + gc1, ld_w1);
    __syncthreads();
    bf16x8 af[4], bw[2];
#pragma unroll
    for (int i = 0; i < 4; i++) {
      int row = wm + i * 16 + qr;
      af[i] = *(const bf16x8*)(As + row * 32 + (quad ^ ((row >> 1) & 3)) * 8);
    }
#pragma unroll
    for (int j = 0; j < 2; j++) {
      int row = wn + j * 16 + qr;
      bw[j] = *(const bf16x8*)(Ws + row * 32 + (quad ^ ((row >> 1) & 3)) * 8);
    }
#pragma unroll
    for (int i = 0; i < 4; i++)
#pragma unroll
      for (int j = 0; j < 2; j++)
        acc[i][j] = __builtin_amdgcn_mfma_f32_16x16x32_bf16(af[i], bw[j], acc[i][j], 0, 0, 0);
    __syncthreads();
  }
#pragma unroll
  for (int i = 0; i < 4; i++)
#pragma unroll
    for (int j = 0; j < 2; j++)
#pragma unroll
      for (int r = 0; r < 4; r++) {
        int row = m0 + wm + i * 16 + quad * 4 + r;
        int col = n0 + wn + j * 16 + qr;
        float v = acc[i][j][r];
        if (WRITE_F32) ((float*)C)[(size_t)row * N + col] = v;
        else           ((u16*)C)[(size_t)row * N + col] = f2bf(v);
      }
}

// ---------------- fused attention v4: P stays in registers ----------------
// Block = (q-tile 128, h, b) x 512 threads = 8 waves: wave w -> qh=w>>1 (q-stripe
// 32), sh=w&1 (s-stripe 64). St = K@Q^T in C-layout == A-operand layout of
// mfma_f32_16x16x16_bf16 -> PV directly from registers, no LDS round-trip.
// Each wave accumulates O-partial[q32][d64] over its s-stripe; one LDS reduce
// at the end. 2 barriers/iter. LDS 33 KB -> 2 blocks/CU, grid 512 = 1 round.
__global__ __launch_bounds__(512, 4) void attn_k(const u16* __restrict__ RQ,
                                                 const u16* __restrict__ KV,
                                                 const u16* __restrict__ VT,
                                                 const u64* __restrict__ mb64,
                                                 const float* __restrict__ nbias,
                                                 u16* __restrict__ O) {
  __shared__ char LB[33792];
  u16* Ks    = (u16*)LB;             // [128 s][64 d]  16 KB, chunk^(s&7) swizzle
  u16* Vts   = (u16*)(LB + 16384);   // [64 d][128 s]  16 KB, chunk^(d&7) swizzle
  float* denS = (float*)(LB + 32768);// [2 sh][128 q]  1 KB
  f32x4* Xch = (f32x4*)LB;           // epilogue exchange, aliases Ks/Vts (32 KB)

  const int tid = threadIdx.x, lane = tid & 63, w = tid >> 6;
  const int qh = w >> 1, sh = w & 1;
  const int qr = lane & 15, quad = lane >> 4;
  const int q0 = blockIdx.x * 128, h = blockIdx.y, b = blockIdx.z;
  const u16* rqb = RQ + ((size_t)(b * Qq + q0)) * Dd + h * AD;
  const u16* kb  = KV + ((size_t)b * Ss) * (2 * Dd) + h * AD;
  const u16* vtb = VT + ((size_t)(b * Hh + h)) * AD * Ss;
  const u64* mbase = mb64 + ((size_t)(b * Qq + q0)) * 32;
  const float nb = nbias[0];

  // persistent Q fragments (B operand: n=q, k=d), from global (L2-hot)
  bf16x8 bq[2][2];
#pragma unroll
  for (int j = 0; j < 2; j++)
#pragma unroll
    for (int kk = 0; kk < 2; kk++)
      bq[j][kk] = *(const bf16x8*)(rqb + (size_t)(qh * 32 + j * 16 + qr) * Dd +
                                   kk * 32 + quad * 8);

  f32x4 acc[2][4] = {};              // O-partial[q: j*16+quad*4+r][d: nn*16+qr]
  float den[2] = {0.f, 0.f};

  const int krS = tid >> 3, kcS = tid & 7;     // Ks staging: 64 rows x 8 chunks / issue
  const int vrS = tid >> 4, vcS = tid & 15;    // Vts staging: 32 rows x 16 chunks / issue

  for (int t = 0; t < 16; t++) {
    __syncthreads();   // prev iter's LDS reads done
    const int s0 = t * 128;
#pragma unroll
    for (int is = 0; is < 2; is++) {
      int row = is * 64 + krS;
      gld16(kb + (size_t)(s0 + row) * (2 * Dd) + ((kcS ^ (row & 7)) * 8),
            Ks + row * 64 + kcS * 8);
    }
#pragma unroll
    for (int is = 0; is < 2; is++) {
      int row = is * 32 + vrS;
      gld16(vtb + (size_t)row * Ss + s0 + ((vcS ^ (row & 7)) * 8),
            Vts + row * 128 + vcS * 8);
    }
    u64 mw[2];
#pragma unroll
    for (int j = 0; j < 2; j++)
      mw[j] = mbase[(size_t)(qh * 32 + j * 16 + qr) * 32 + (t << 1) + sh];
    __syncthreads();   // tiles staged (barrier drains vmcnt)

#pragma unroll
    for (int mi = 0; mi < 4; mi++) {
      // scores for s-16-granule (sh*4+mi): St = K @ Q^T
      int krow = sh * 64 + mi * 16 + qr;
      const u16* kbase = Ks + krow * 64;
      bf16x8 ak0 = *(const bf16x8*)(kbase + ((quad)     ^ (krow & 7)) * 8);
      bf16x8 ak1 = *(const bf16x8*)(kbase + ((quad + 4) ^ (krow & 7)) * 8);
      f32x4 asc[2] = {};
#pragma unroll
      for (int j = 0; j < 2; j++) {
        asc[j] = __builtin_amdgcn_mfma_f32_16x16x32_bf16(ak0, bq[j][0], asc[j], 0, 0, 0);
        asc[j] = __builtin_amdgcn_mfma_f32_16x16x32_bf16(ak1, bq[j][1], asc[j], 0, 0, 0);
      }
      // mask + relu^2 -> bf16 (truncate); same values into denominator; pack A-frag
      union { u32 w2[2]; bf16x4 v; } pk[2];
#pragma unroll
      for (int j = 0; j < 2; j++) {
        u32 mm = (u32)(mw[j] >> (mi * 16 + quad * 4)) & 0xFu;
        u32 th[4];
#pragma unroll
        for (int r = 0; r < 4; r++) {
          float v = __builtin_fmaf(asc[j][r], 0.125f, nb);
          float tt = fmaxf(v, 0.f);
          tt = tt * tt;
          if ((mm >> r) & 1) tt = 0.f;
          union { float f; u32 u; } cv; cv.f = tt;
          th[r] = cv.u & 0xffff0000u;
          union { u32 u; float f; } tv; tv.u = th[r];
          den[j] += tv.f;
        }
        pk[j].w2[0] = (th[0] >> 16) | th[1];
        pk[j].w2[1] = (th[2] >> 16) | th[3];
      }
      // PV: acc[j][nn] += P(16x16) @ V(16x16) via K=16 MFMA, A from registers
      int g = sh * 16 + mi * 4 + quad;          // 8B granule of s
#pragma unroll
      for (int nn = 0; nn < 4; nn++) {
        int vrow = nn * 16 + qr;
        bf16x4 bv = *(const bf16x4*)(Vts + vrow * 128 + (g ^ ((vrow & 7) << 1)) * 4);
#pragma unroll
        for (int j = 0; j < 2; j++)
          acc[j][nn] = __builtin_amdgcn_mfma_f32_16x16x16bf16_1k(pk[j].v, bv, acc[j][nn], 0, 0, 0);
      }
    }
  }

  __syncthreads();   // last PV reads done -> LB reusable

  // denominator: reduce over quads, publish per (sh, q) to LDS
#pragma unroll
  for (int j = 0; j < 2; j++) {
    den[j] += __shfl_xor(den[j], 16, 64);
    den[j] += __shfl_xor(den[j], 32, 64);
  }
  if (quad == 0) {
#pragma unroll
    for (int j = 0; j < 2; j++)
      denS[sh * 128 + qh * 32 + j * 16 + qr] = den[j];
  }
  // O-partial exchange: sh==1 waves write, sh==0 waves add
  if (sh == 1) {
#pragma unroll
    for (int j = 0; j < 2; j++)
#pragma unroll
      for (int nn = 0; nn < 4; nn++)
        Xch[qh * 512 + (j * 4 + nn) * 64 + lane] = acc[j][nn];
  }
  __syncthreads();

  if (sh == 0) {
    u16* ob = O + ((size_t)(b * Qq + q0)) * Dd + h * AD;
#pragma unroll
    for (int j = 0; j < 2; j++) {
      float rc[4];
#pragma unroll
      for (int r = 0; r < 4; r++) {
        int ql = qh * 32 + j * 16 + quad * 4 + r;
        rc[r] = 1.f / (denS[ql] + denS[128 + ql] + 1e-32f);
      }
#pragma unroll
      for (int nn = 0; nn < 4; nn++) {
        f32x4 s4 = acc[j][nn];
        f32x4 p4 = Xch[qh * 512 + (j * 4 + nn) * 64 + lane];
#pragma unroll
        for (int r = 0; r < 4; r++) {
          int ql = qh * 32 + j * 16 + quad * 4 + r;
          ob[(size_t)ql * Dd + nn * 16 + qr] = f2bf((s4[r] + p4[r]) * rc[r]);
        }
      }
    }
  }
}

// ---------------- launch ----------------
extern "C" void kernel_launch(void* const* d_in, const int* in_sizes, int n_in,
                              void* d_out, int out_size, void* d_ws, size_t ws_size,
                              hipStream_t stream) {
  const float* iQ   = (const float*)d_in[0];
  const float* iK   = (const float*)d_in[1];
  const int*   mask = (const int*)d_in[2];
  const float* Wq   = (const float*)d_in[3];
  const float* Wkv  = (const float*)d_in[4];
  const float* Wo   = (const float*)d_in[5];
  const float* nb   = (const float*)d_in[6];

  char* ws = (char*)d_ws;
  u16* Qb   = (u16*)(ws + (size_t)0);          // 8 MB
  u16* Kb   = (u16*)(ws + ((size_t)8  << 20)); // 8 MB
  u16* Wqb  = (u16*)(ws + ((size_t)16 << 20)); // 2 MB
  u16* Wkvb = (u16*)(ws + ((size_t)18 << 20)); // 4 MB
  u16* Wob  = (u16*)(ws + ((size_t)22 << 20)); // 2 MB
  u16* RQ   = (u16*)(ws + ((size_t)24 << 20)); // 8 MB
  u16* KV   = (u16*)(ws + ((size_t)32 << 20)); // 16 MB
  u16* Obuf = (u16*)(ws + ((size_t)48 << 20)); // 8 MB
  u16* VT   = (u16*)(ws + ((size_t)56 << 20)); // 8 MB
  u64* MB   = (u64*)(ws + ((size_t)64 << 20)); // 1 MB  -- total 65 MB

  cast_all_k<<<12288, 256, 0, stream>>>(iQ, iK, Wq, Wkv, Wo, Qb, Kb, Wqb, Wkvb, Wob);
  maskpack_k<<<512, 256, 0, stream>>>(mask, MB);

  gemm_bt<0><<<dim3(32, 16), 256, 0, stream>>>(Qb, Wqb, RQ, 4096, 1024, 1024);
  gemm_bt<0><<<dim3(32, 32), 256, 0, stream>>>(Kb, Wkvb, KV, 4096, 2048, 1024);
  vtrans_k<<<dim3(32, 16, 2), 256, 0, stream>>>(KV, VT);

  attn_k<<<dim3(16, 16, 2), 512, 0, stream>>>(RQ, KV, VT, MB, nb, Obuf);

  gemm_bt<1><<<dim3(32, 16), 256, 0, stream>>>(Obuf, Wob, d_out, 4096, 1024, 1024);
}

// Round 5
// 229.286 us; speedup vs baseline: 1.4978x; 1.1661x over previous
//
#include <hip/hip_runtime.h>

// Problem constants
#define Bb 2
#define Qq 2048
#define Ss 2048
#define Dd 1024
#define Hh 16
#define AD 64
#define KK 1024

typedef __attribute__((ext_vector_type(8))) short bf16x8;
typedef __attribute__((ext_vector_type(4))) short bf16x4;
typedef __attribute__((ext_vector_type(4))) float f32x4;
typedef unsigned short u16;
typedef unsigned int u32;
typedef unsigned long long u64;

__device__ __forceinline__ u16 f2bf(float f) {
  union { float f; u32 u; } v; v.f = f;
  u32 r = v.u + 0x7fffu + ((v.u >> 16) & 1u);  // RNE
  return (u16)(r >> 16);
}

// async 16B global->LDS DMA (dest = wave-uniform base + lane*16)
__device__ __forceinline__ void gld16(const u16* g, u16* l) {
  __builtin_amdgcn_global_load_lds(
      (const __attribute__((address_space(1))) unsigned int*)g,
      (__attribute__((address_space(3))) unsigned int*)l, 16, 0, 0);
}

// ---------------- fused f32 -> bf16 cast for all 5 inputs ----------------
__global__ __launch_bounds__(256) void cast_all_k(const float* __restrict__ iQ,
                                                  const float* __restrict__ iK,
                                                  const float* __restrict__ Wq,
                                                  const float* __restrict__ Wkv,
                                                  const float* __restrict__ Wo,
                                                  u16* __restrict__ Qb, u16* __restrict__ Kb,
                                                  u16* __restrict__ Wqb, u16* __restrict__ Wkvb,
                                                  u16* __restrict__ Wob) {
  int i = blockIdx.x * 256 + threadIdx.x;   // float4 index, total 3145728
  const float* src; u16* dst; int off;
  if (i < 1048576)      { src = iQ;  dst = Qb;   off = 0; }
  else if (i < 2097152) { src = iK;  dst = Kb;   off = 1048576; }
  else if (i < 2359296) { src = Wq;  dst = Wqb;  off = 2097152; }
  else if (i < 2883584) { src = Wkv; dst = Wkvb; off = 2359296; }
  else                  { src = Wo;  dst = Wob;  off = 2883584; }
  int j = i - off;
  float4 v = ((const float4*)src)[j];
  ushort4 o;
  o.x = f2bf(v.x); o.y = f2bf(v.y); o.z = f2bf(v.z); o.w = f2bf(v.w);
  ((ushort4*)dst)[j] = o;
}

// ---------------- mask bit-pack: int32[b][q][s] -> u64[b][q][s/64] ----------------
__global__ __launch_bounds__(256) void maskpack_k(const int* __restrict__ mask,
                                                  u64* __restrict__ mb64) {
  int flat = blockIdx.x * 256 + threadIdx.x;   // total 2*2048*32 = 131072
  int st = flat & 31;
  int q  = (flat >> 5) & 2047;
  int b  = flat >> 16;
  const int4* src = (const int4*)(mask + ((size_t)(b * Qq + q)) * Ss + st * 64);
  u64 bits = 0;
#pragma unroll
  for (int c = 0; c < 16; c++) {
    int4 v = src[c];
    bits |= (u64)(v.x != 0) << (c * 4 + 0);
    bits |= (u64)(v.y != 0) << (c * 4 + 1);
    bits |= (u64)(v.z != 0) << (c * 4 + 2);
    bits |= (u64)(v.w != 0) << (c * 4 + 3);
  }
  mb64[flat] = bits;
}

// ---------------- fused projection GEMM (Q-proj + KV-proj + V-transpose) --------
// 128x64 tile, BK=64, 256 thr. blocks [0,512): RQ = (Qb@Wq^T)*0.125;
// [512,1536): KV-proj -- K-half tiles -> KV buffer; V-half tiles -> VT[b][h][d][s]
// via LDS transpose. LDS rows 64 u16 = 8 chunks of 16B, chunk c at c^(row&7).
__global__ __launch_bounds__(256, 4) void proj_k(const u16* __restrict__ Qb,
                                                 const u16* __restrict__ Kb,
                                                 const u16* __restrict__ Wqb,
                                                 const u16* __restrict__ Wkvb,
                                                 u16* __restrict__ RQ,
                                                 u16* __restrict__ KV,
                                                 u16* __restrict__ VT) {
  __shared__ u16 LDS[128 * 64 + 64 * 64];   // As[128][64] + Ws[64][64] = 24 KB
  u16* As = LDS;
  u16* Ws = LDS + 128 * 64;
  u16* Tt = LDS;                            // epilogue alias [64][136]
  const int tid = threadIdx.x;
  const int lane = tid & 63, wave = tid >> 6;
  const int qr = lane & 15, quad = lane >> 4;
  const int bid = blockIdx.x;
  const bool isQ = bid < 512;
  const int b2 = isQ ? bid : bid - 512;
  const int m0 = (b2 & 31) * 128;
  const int n0 = (b2 >> 5) * 64;
  const u16* A = isQ ? Qb : Kb;
  const u16* W = isQ ? Wqb : Wkvb;
  const int wm = (wave >> 1) * 64, wn = (wave & 1) * 32;
  const int qs = qr & 7;

  // staging pointers (4 A-issues, 2 W-issues), swizzled source, lane-contig dest
  const int sr = tid >> 3, sc = tid & 7;
  const u16 *aP[4], *wP[2];
  u16 *aL[4], *wL[2];
#pragma unroll
  for (int is = 0; is < 4; is++) {
    int row = is * 32 + sr;
    aP[is] = A + (size_t)(m0 + row) * KK + ((sc ^ (row & 7)) * 8);
    aL[is] = As + row * 64 + sc * 8;
  }
#pragma unroll
  for (int is = 0; is < 2; is++) {
    int row = is * 32 + sr;
    wP[is] = W + (size_t)(n0 + row) * KK + ((sc ^ (row & 7)) * 8);
    wL[is] = Ws + row * 64 + sc * 8;
  }

  f32x4 acc[4][2] = {};

  for (int k0 = 0; k0 < KK; k0 += 64) {
#pragma unroll
    for (int is = 0; is < 4; is++) gld16(aP[is] + k0, aL[is]);
#pragma unroll
    for (int is = 0; is < 2; is++) gld16(wP[is] + k0, wL[is]);
    __syncthreads();
#pragma unroll
    for (int kk = 0; kk < 2; kk++) {
      bf16x8 af[4], bw[2];
#pragma unroll
      for (int i = 0; i < 4; i++)
        af[i] = *(const bf16x8*)(As + (wm + i * 16 + qr) * 64 + (((kk * 4 + quad) ^ qs) * 8));
#pragma unroll
      for (int j = 0; j < 2; j++)
        bw[j] = *(const bf16x8*)(Ws + (wn + j * 16 + qr) * 64 + (((kk * 4 + quad) ^ qs) * 8));
#pragma unroll
      for (int i = 0; i < 4; i++)
#pragma unroll
        for (int j = 0; j < 2; j++)
          acc[i][j] = __builtin_amdgcn_mfma_f32_16x16x32_bf16(af[i], bw[j], acc[i][j], 0, 0, 0);
    }
    __syncthreads();
  }

  if (isQ) {
#pragma unroll
    for (int i = 0; i < 4; i++)
#pragma unroll
      for (int j = 0; j < 2; j++)
#pragma unroll
        for (int r = 0; r < 4; r++) {
          int row = m0 + wm + i * 16 + quad * 4 + r;
          int col = n0 + wn + j * 16 + qr;
          RQ[(size_t)row * 1024 + col] = f2bf(acc[i][j][r] * 0.125f);  // fold QK scale
        }
  } else if (n0 < 1024) {
    // K-half -> KV buffer
#pragma unroll
    for (int i = 0; i < 4; i++)
#pragma unroll
      for (int j = 0; j < 2; j++)
#pragma unroll
        for (int r = 0; r < 4; r++) {
          int row = m0 + wm + i * 16 + quad * 4 + r;
          int col = n0 + wn + j * 16 + qr;
          KV[(size_t)row * 2048 + col] = f2bf(acc[i][j][r]);
        }
  } else {
    // V-half -> VT[b][h][d][s] via LDS transpose (Tt[64 d][136 s-pad])
#pragma unroll
    for (int i = 0; i < 4; i++)
#pragma unroll
      for (int j = 0; j < 2; j++)
#pragma unroll
        for (int r = 0; r < 4; r++) {
          int srow = wm + i * 16 + quad * 4 + r;          // local s
          int d    = wn + j * 16 + qr;                    // local d
          Tt[d * 136 + srow] = f2bf(acc[i][j][r]);
        }
    __syncthreads();
    const int h = (n0 - 1024) >> 6;
    const int bb = m0 >> 11, sbase = m0 & 2047;
    u16* vdst = VT + (((size_t)(bb * Hh + h)) * AD) * Ss;
    const int d = tid >> 2;
#pragma unroll
    for (int ic = 0; ic < 4; ic++) {
      int ch = ic * 4 + (tid & 3);
      *(int4*)(vdst + (size_t)d * Ss + sbase + ch * 8) = *(const int4*)(Tt + d * 136 + ch * 8);
    }
  }
}

// ---------------- O-projection: d_out = Obuf @ Wo^T (f32 out) ----------------
__global__ __launch_bounds__(256, 4) void oproj_k(const u16* __restrict__ A,
                                                  const u16* __restrict__ W,
                                                  float* __restrict__ C) {
  __shared__ u16 LDS[128 * 64 + 64 * 64];
  u16* As = LDS;
  u16* Ws = LDS + 128 * 64;
  const int tid = threadIdx.x;
  const int lane = tid & 63, wave = tid >> 6;
  const int qr = lane & 15, quad = lane >> 4;
  const int m0 = (blockIdx.x & 31) * 128;
  const int n0 = (blockIdx.x >> 5) * 64;
  const int wm = (wave >> 1) * 64, wn = (wave & 1) * 32;
  const int qs = qr & 7;
  const int sr = tid >> 3, sc = tid & 7;
  const u16 *aP[4], *wP[2];
  u16 *aL[4], *wL[2];
#pragma unroll
  for (int is = 0; is < 4; is++) {
    int row = is * 32 + sr;
    aP[is] = A + (size_t)(m0 + row) * KK + ((sc ^ (row & 7)) * 8);
    aL[is] = As + row * 64 + sc * 8;
  }
#pragma unroll
  for (int is = 0; is < 2; is++) {
    int row = is * 32 + sr;
    wP[is] = W + (size_t)(n0 + row) * KK + ((sc ^ (row & 7)) * 8);
    wL[is] = Ws + row * 64 + sc * 8;
  }
  f32x4 acc[4][2] = {};
  for (int k0 = 0; k0 < KK; k0 += 64) {
#pragma unroll
    for (int is = 0; is < 4; is++) gld16(aP[is] + k0, aL[is]);
#pragma unroll
    for (int is = 0; is < 2; is++) gld16(wP[is] + k0, wL[is]);
    __syncthreads();
#pragma unroll
    for (int kk = 0; kk < 2; kk++) {
      bf16x8 af[4], bw[2];
#pragma unroll
      for (int i = 0; i < 4; i++)
        af[i] = *(const bf16x8*)(As + (wm + i * 16 + qr) * 64 + (((kk * 4 + quad) ^ qs) * 8));
#pragma unroll
      for (int j = 0; j < 2; j++)
        bw[j] = *(const bf16x8*)(Ws + (wn + j * 16 + qr) * 64 + (((kk * 4 + quad) ^ qs) * 8));
#pragma unroll
      for (int i = 0; i < 4; i++)
#pragma unroll
        for (int j = 0; j < 2; j++)
          acc[i][j] = __builtin_amdgcn_mfma_f32_16x16x32_bf16(af[i], bw[j], acc[i][j], 0, 0, 0);
    }
    __syncthreads();
  }
#pragma unroll
  for (int i = 0; i < 4; i++)
#pragma unroll
    for (int j = 0; j < 2; j++)
#pragma unroll
      for (int r = 0; r < 4; r++) {
        int row = m0 + wm + i * 16 + quad * 4 + r;
        int col = n0 + wn + j * 16 + qr;
        C[(size_t)row * 1024 + col] = acc[i][j][r];
      }
}

// ---------------- fused attention v5 ----------------
// Block = (q-tile 128, h, b) x 512 thr (8 waves: qh=w>>1, sh=w&1), s-tile 256
// (8 iters, 2 barriers each). P in registers (C-layout == A-layout of
// mfma_16x16x16). Denominator via MFMA with all-ones B (epilogue-local 1/den).
// nbias folded into accumulator init; 0.125 pre-folded into RQ.
__global__ __launch_bounds__(512, 4) void attn_k(const u16* __restrict__ RQ,
                                                 const u16* __restrict__ KV,
                                                 const u16* __restrict__ VT,
                                                 const u64* __restrict__ mb64,
                                                 const float* __restrict__ nbias,
                                                 u16* __restrict__ O) {
  __shared__ char LB[65536];
  u16* Ks  = (u16*)LB;             // [256 s][64 d] 32 KB, chunk^(s&7) -> qr&7
  u16* Vts = (u16*)(LB + 32768);   // [64 d][256 s] 32 KB, chunk^(d&7)
  f32x4* Xch = (f32x4*)LB;         // epilogue exchange (40 KB), aliases

  const int tid = threadIdx.x, lane = tid & 63, w = tid >> 6;
  const int qh = w >> 1, sh = w & 1;
  const int qr = lane & 15, quad = lane >> 4;
  const int quad4 = quad * 4, qs = qr & 7;
  const int q0 = blockIdx.x * 128, h = blockIdx.y, b = blockIdx.z;
  const u16* rqb = RQ + ((size_t)(b * Qq + q0)) * Dd + h * AD;
  const u16* kb  = KV + ((size_t)b * Ss) * 2048 + h * AD;
  const u16* vtb = VT + ((size_t)(b * Hh + h)) * AD * Ss;
  const u64* mbase = mb64 + ((size_t)(b * Qq + q0)) * 32;
  const float nb = nbias[0];

  // persistent Q fragments (B operand: n=q, k=d)
  bf16x8 bq[2][2];
#pragma unroll
  for (int j = 0; j < 2; j++)
#pragma unroll
    for (int kk = 0; kk < 2; kk++)
      bq[j][kk] = *(const bf16x8*)(rqb + (size_t)(qh * 32 + j * 16 + qr) * Dd +
                                   kk * 32 + quad * 8);

  // staging pointers
  const u16 *kP[4], *vP[4];
  u16 *kL[4], *vL[4];
  {
    const int r8 = tid >> 3, c8 = tid & 7;
#pragma unroll
    for (int is = 0; is < 4; is++) {
      int row = is * 64 + r8;
      kP[is] = kb + (size_t)row * 2048 + ((c8 ^ (row & 7)) * 8);
      kL[is] = Ks + row * 64 + c8 * 8;
    }
    const int r32 = tid >> 5, c32 = tid & 31;
#pragma unroll
    for (int is = 0; is < 4; is++) {
      int row = is * 16 + r32;
      vP[is] = vtb + (size_t)row * Ss + ((c32 ^ (row & 7)) * 8);
      vL[is] = Vts + row * 256 + c32 * 8;
    }
  }

  const bf16x4 vones = { (short)0x3F80, (short)0x3F80, (short)0x3F80, (short)0x3F80 };
  f32x4 acc[2][4] = {};
  f32x4 accd[2] = {};

  // QK frag bases (swizzle collapses to qr&7 -> immediate-offset ds_reads)
  const u16* kfr = Ks + (sh * 128 + qr) * 64;
  const u16* kfr0 = kfr + ((quad ^ qs) * 8);
  const u16* kfr1 = kfr + (((quad + 4) ^ qs) * 8);

  for (int t = 0; t < 8; t++) {
    __syncthreads();
#pragma unroll
    for (int is = 0; is < 4; is++) gld16(kP[is] + (size_t)t * 524288, kL[is]);
#pragma unroll
    for (int is = 0; is < 4; is++) gld16(vP[is] + t * 256, vL[is]);
    // mask words: 2 u64 per j (this wave's 128-s stripe)
    u64 mw[2][2];
#pragma unroll
    for (int j = 0; j < 2; j++) {
      const u64* mp = mbase + (size_t)(qh * 32 + j * 16 + qr) * 32 + t * 4 + sh * 2;
      mw[j][0] = mp[0];
      mw[j][1] = mp[1];
    }
    __syncthreads();

#pragma unroll
    for (int mi = 0; mi < 8; mi++) {
      bf16x8 ak0 = *(const bf16x8*)(kfr0 + mi * 1024);
      bf16x8 ak1 = *(const bf16x8*)(kfr1 + mi * 1024);
      f32x4 asc0 = { nb, nb, nb, nb };
      f32x4 asc1 = { nb, nb, nb, nb };
      asc0 = __builtin_amdgcn_mfma_f32_16x16x32_bf16(ak0, bq[0][0], asc0, 0, 0, 0);
      asc0 = __builtin_amdgcn_mfma_f32_16x16x32_bf16(ak1, bq[0][1], asc0, 0, 0, 0);
      asc1 = __builtin_amdgcn_mfma_f32_16x16x32_bf16(ak0, bq[1][0], asc1, 0, 0, 0);
      asc1 = __builtin_amdgcn_mfma_f32_16x16x32_bf16(ak1, bq[1][1], asc1, 0, 0, 0);

      union { u32 w2[2]; bf16x4 v; } pk[2];
#pragma unroll
      for (int j = 0; j < 2; j++) {
        f32x4 asc = j ? asc1 : asc0;
        u32 mm = (u32)(mw[j][mi >> 2] >> ((mi & 3) * 16 + quad4)) & 0xFu;
        u32 th[4];
#pragma unroll
        for (int r = 0; r < 4; r++) {
          float tt = fmaxf(asc[r], 0.f);
          tt = tt * tt;
          if ((mm >> r) & 1) tt = 0.f;
          union { float f; u32 u; } cv; cv.f = tt;
          th[r] = cv.u;
        }
        pk[j].w2[0] = __builtin_amdgcn_perm(th[1], th[0], 0x07060302u);
        pk[j].w2[1] = __builtin_amdgcn_perm(th[3], th[2], 0x07060302u);
        accd[j] = __builtin_amdgcn_mfma_f32_16x16x16bf16_1k(pk[j].v, vones, accd[j], 0, 0, 0);
      }
      // PV with B from Vts (granule swizzle: key (qr&7)<<1)
      int g = ((sh * 32 + mi * 4 + quad) ^ (qs << 1)) * 4;
#pragma unroll
      for (int nn = 0; nn < 4; nn++) {
        bf16x4 bv = *(const bf16x4*)(Vts + (nn * 16 + qr) * 256 + g);
        acc[0][nn] = __builtin_amdgcn_mfma_f32_16x16x16bf16_1k(pk[0].v, bv, acc[0][nn], 0, 0, 0);
        acc[1][nn] = __builtin_amdgcn_mfma_f32_16x16x16bf16_1k(pk[1].v, bv, acc[1][nn], 0, 0, 0);
      }
    }
  }

  __syncthreads();   // LB reusable
  // cross-(sh) partial exchange: sh==1 writes, sh==0 reduces + normalizes + stores
  if (sh == 1) {
#pragma unroll
    for (int j = 0; j < 2; j++) {
#pragma unroll
      for (int nn = 0; nn < 4; nn++)
        Xch[qh * 640 + (j * 4 + nn) * 64 + lane] = acc[j][nn];
      Xch[qh * 640 + (8 + j) * 64 + lane] = accd[j];
    }
  }
  __syncthreads();
  if (sh == 0) {
    u16* ob = O + ((size_t)(b * Qq + q0)) * Dd + h * AD;
#pragma unroll
    for (int j = 0; j < 2; j++) {
      f32x4 dpart = Xch[qh * 640 + (8 + j) * 64 + lane];
      float rc[4];
#pragma unroll
      for (int r = 0; r < 4; r++)
        rc[r] = 1.f / (accd[j][r] + dpart[r] + 1e-32f);
#pragma unroll
      for (int nn = 0; nn < 4; nn++) {
        f32x4 p4 = Xch[qh * 640 + (j * 4 + nn) * 64 + lane];
#pragma unroll
        for (int r = 0; r < 4; r++) {
          int ql = qh * 32 + j * 16 + quad * 4 + r;
          ob[(size_t)ql * Dd + nn * 16 + qr] = f2bf((acc[j][nn][r] + p4[r]) * rc[r]);
        }
      }
    }
  }
}

// ---------------- launch ----------------
extern "C" void kernel_launch(void* const* d_in, const int* in_sizes, int n_in,
                              void* d_out, int out_size, void* d_ws, size_t ws_size,
                              hipStream_t stream) {
  const float* iQ   = (const float*)d_in[0];
  const float* iK   = (const float*)d_in[1];
  const int*   mask = (const int*)d_in[2];
  const float* Wq   = (const float*)d_in[3];
  const float* Wkv  = (const float*)d_in[4];
  const float* Wo   = (const float*)d_in[5];
  const float* nb   = (const float*)d_in[6];

  char* ws = (char*)d_ws;
  u16* Qb   = (u16*)(ws + (size_t)0);          // 8 MB
  u16* Kb   = (u16*)(ws + ((size_t)8  << 20)); // 8 MB
  u16* Wqb  = (u16*)(ws + ((size_t)16 << 20)); // 2 MB
  u16* Wkvb = (u16*)(ws + ((size_t)18 << 20)); // 4 MB
  u16* Wob  = (u16*)(ws + ((size_t)22 << 20)); // 2 MB
  u16* RQ   = (u16*)(ws + ((size_t)24 << 20)); // 8 MB  (pre-scaled by 0.125)
  u16* KV   = (u16*)(ws + ((size_t)32 << 20)); // 16 MB (K-half used)
  u16* Obuf = (u16*)(ws + ((size_t)48 << 20)); // 8 MB
  u16* VT   = (u16*)(ws + ((size_t)56 << 20)); // 8 MB
  u64* MB   = (u64*)(ws + ((size_t)64 << 20)); // 1 MB  -- total 65 MB

  cast_all_k<<<12288, 256, 0, stream>>>(iQ, iK, Wq, Wkv, Wo, Qb, Kb, Wqb, Wkvb, Wob);
  maskpack_k<<<512, 256, 0, stream>>>(mask, MB);

  proj_k<<<1536, 256, 0, stream>>>(Qb, Kb, Wqb, Wkvb, RQ, KV, VT);

  attn_k<<<dim3(16, 16, 2), 512, 0, stream>>>(RQ, KV, VT, MB, nb, Obuf);

  oproj_k<<<512, 256, 0, stream>>>(Obuf, Wob, (float*)d_out);
}